// Round 12
// baseline (1693.578 us; speedup 1.0000x reference)
//
#include <hip/hip_runtime.h>
#include <stdint.h>

// SelfAttention: B=64,N=8,L=128,E=768,H=12,T=64  (S=512 sets of 128 tokens)
//
// gemm8p<OUTF32>: 256x256 tile, BK=64 (12 K-tiles), 8 waves, ring-2 128KiB
// dynamic LDS, 4-phase-per-K-tile quadrant schedule (r10-proven), K-loop
// unrolled in (buf0,buf1) pairs so all LDS bases are compile-time constants
// (hoists ds_read address arith out of VALU), both B fragment sets kept live
// (20 ds_read_b128/K-tile), last tile specialized (no staging/barriers).
// ONE counted vmcnt(2)/K-tile. swz64 LDS (0-conflict), XCD-chunked grids.

#define EE 768
#define SLOT 50331648L   // shorts per [65536][768] slot

typedef short s16x8 __attribute__((ext_vector_type(8)));
typedef float f32x4 __attribute__((ext_vector_type(4)));

__device__ __forceinline__ short f2bf(float f){
  union { float fv; uint32_t u; } v; v.fv = f;
  uint32_t r = (v.u + 0x7fffu + ((v.u >> 16) & 1u)) >> 16;  // RNE
  return (short)r;
}

__device__ __forceinline__ void gld_lds16(const short* g, short* l){
  __builtin_amdgcn_global_load_lds(
      (const __attribute__((address_space(1))) void*)(uintptr_t)g,
      (__attribute__((address_space(3))) void*)(uintptr_t)l,
      16, 0, 0);
}

// bijective XCD chunking (m204)
__device__ __forceinline__ int xcd_swz(int bid, int nwg){
  int xcd = bid & 7, loc = bid >> 3;
  int q = nwg >> 3, r = nwg & 7;
  return (xcd < r ? xcd * (q + 1) : r * (q + 1) + (xcd - r) * q) + loc;
}

// swizzles (involutions)
__device__ __forceinline__ int swz64(int row, int c){ return c ^ ((row & 7) << 3); }
__device__ __forceinline__ int swz32(int row, int c){ return c ^ (((row >> 1) & 3) << 3); }

// ---------------- casts / small helpers ----------------
__global__ __launch_bounds__(256) void cast_bf16_k(const float* __restrict__ src,
                                                   short* __restrict__ dst,
                                                   long n, float scale){
  long i = ((long)blockIdx.x * 256 + threadIdx.x) * 8;
  if(i >= n) return;
  float4 a = *(const float4*)(src + i);
  float4 b = *(const float4*)(src + i + 4);
  s16x8 o;
  o[0]=f2bf(a.x*scale); o[1]=f2bf(a.y*scale); o[2]=f2bf(a.z*scale); o[3]=f2bf(a.w*scale);
  o[4]=f2bf(b.x*scale); o[5]=f2bf(b.y*scale); o[6]=f2bf(b.z*scale); o[7]=f2bf(b.w*scale);
  *(s16x8*)(dst + i) = o;
}

__global__ __launch_bounds__(256) void cvec_k(const float* __restrict__ Wf,
                                              const float* __restrict__ bv,
                                              const float* __restrict__ bfv,
                                              float* __restrict__ c){
  int e = blockIdx.x * 256 + threadIdx.x;
  if(e >= EE) return;
  float s = bfv[e];
  for(int k = 0; k < EE; ++k) s += Wf[(long)e * EE + k] * bv[k];
  c[e] = s;
}

__global__ __launch_bounds__(256) void bias_build(const float* __restrict__ bq,
                                                  float* __restrict__ biasQP){
  int i = blockIdx.x * 256 + threadIdx.x;
  if(i < 9984) biasQP[i] = (i < 9216) ? bq[i] : 0.f;
}

// ============ 4-phase 256² GEMM, BK=64, ring-2 (dynamic 128 KiB LDS) ============
// Out[g] = A @ W[wh]^T + bias[wh];  K=768 = 12 K-tiles of 64.
template<bool OUTF32>
__global__ __launch_bounds__(512, 1) void gemm8p(const short* __restrict__ A,
                                                 const short* __restrict__ W,
                                                 const float* __restrict__ bias,
                                                 void* __restrict__ OutBase,
                                                 int hBase, int nSub, int pSub){
  extern __shared__ short lds[];   // 2 bufs × (A 16384 | B 16384 shorts)
  const int tid = threadIdx.x, lane = tid & 63, w = tid >> 6;
  const int wr = w >> 2, wc = w & 3;           // 2x4 wave grid; wave owns 128x64
  const int bid = xcd_swz(blockIdx.x, nSub * 768);
  const int g = bid / 768, rb = bid - g * 768;
  const int rowBlk = rb / 3, colBlk = rb - rowBlk * 3;
  const long rowA0 = (long)rowBlk * 256;
  const int colB0 = colBlk * 256;
  const int wh = (g == pSub) ? 12 : hBase + g;
  const short* Bm = W + (long)wh * 589824L;

  const int srow = tid >> 3;                    // 0..63
  const int ssw = swz64(srow, (tid & 7) * 8);   // pre-swizzled source col
  const short* gA = A + (rowA0 + srow) * 768 + ssw;
  const short* gB = Bm + (long)(colB0 + srow) * 768 + ssw;

  // stage one half-tile (128 rows = 2 gld_lds): which 0=A0,1=A1,2=B0,3=B1
  auto stageH = [&](short* dstBase, int kt, int which){
    const short* gs = (which < 2 ? gA : gB) + (long)(which & 1) * 98304 + kt;
    short* dst = dstBase + (which >> 1) * 16384 + (which & 1) * 8192 + w * 512;
    gld_lds16(gs, dst);
    gld_lds16(gs + 49152, dst + 4096);
  };

  f32x4 acc[8][4] = {};
  const int fr = lane & 15, fcb = (lane >> 4) * 8;
  s16x8 af[4][2], bf0[2][2], bf1[2][2];

  auto readA = [&](const short* Al, int mh){
    #pragma unroll
    for(int m = 0; m < 4; ++m){
      int row = wr * 128 + (mh * 4 + m) * 16 + fr;
      #pragma unroll
      for(int kk = 0; kk < 2; ++kk)
        af[m][kk] = *(const s16x8*)&Al[row * 64 + swz64(row, kk * 32 + fcb)];
    }
  };
  auto readB = [&](const short* Bl, s16x8 (&bfr)[2][2], int nh){
    #pragma unroll
    for(int n = 0; n < 2; ++n){
      int row = wc * 64 + (nh * 2 + n) * 16 + fr;
      #pragma unroll
      for(int kk = 0; kk < 2; ++kk)
        bfr[n][kk] = *(const s16x8*)&Bl[row * 64 + swz64(row, kk * 32 + fcb)];
    }
  };
  auto mmq = [&](int mh, int nh, s16x8 (&bfr)[2][2]){
    asm volatile("s_waitcnt lgkmcnt(0)" ::: "memory");
    __builtin_amdgcn_s_setprio(1);
    #pragma unroll
    for(int m = 0; m < 4; ++m)
      #pragma unroll
      for(int n = 0; n < 2; ++n)
        #pragma unroll
        for(int kk = 0; kk < 2; ++kk)
          acc[mh*4+m][nh*2+n] = __builtin_amdgcn_mfma_f32_16x16x32_bf16(
              af[m][kk], bfr[n][kk], acc[mh*4+m][nh*2+n], 0, 0, 0);
    __builtin_amdgcn_s_setprio(0);
  };

  // one full K-tile with staging of the next (t < 11 guaranteed by caller)
  auto tileStep = [&](const short* Cb, short* Sb, int kt1){
    stageH(Sb, kt1, 0);
    asm volatile("s_waitcnt vmcnt(2)" ::: "memory");
    asm volatile("s_barrier" ::: "memory");
    readA(Cb, 0); readB(Cb + 16384, bf0, 0);
    mmq(0, 0, bf0);
    asm volatile("s_barrier" ::: "memory");
    readB(Cb + 16384, bf1, 1);
    stageH(Sb, kt1, 1);
    asm volatile("s_barrier" ::: "memory");
    mmq(0, 1, bf1);
    asm volatile("s_barrier" ::: "memory");
    readA(Cb, 1);
    stageH(Sb, kt1, 2);
    asm volatile("s_barrier" ::: "memory");
    mmq(1, 1, bf1);
    asm volatile("s_barrier" ::: "memory");
    stageH(Sb, kt1, 3);
    asm volatile("s_barrier" ::: "memory");
    mmq(1, 0, bf0);
    asm volatile("s_barrier" ::: "memory");
  };

  short* buf0 = lds;
  short* buf1 = lds + 32768;

  // prologue: stage all 4 halves of K-tile 0 into buf0
  stageH(buf0, 0, 0); stageH(buf0, 0, 1); stageH(buf0, 0, 2); stageH(buf0, 0, 3);

  // tiles 0..10 (staging 1..11), compile-time buffer bases
  #pragma unroll 1
  for(int u = 0; u < 5; ++u){
    tileStep(buf0, buf1, (2 * u + 1) * 64);
    tileStep(buf1, buf0, (2 * u + 2) * 64);
  }
  tileStep(buf0, buf1, 11 * 64);   // t=10

  // t=11 (buf1): no staging — drain, read all fragments, 4 MFMA quadrants
  asm volatile("s_waitcnt vmcnt(0)" ::: "memory");
  asm volatile("s_barrier" ::: "memory");
  readA(buf1, 0); readB(buf1 + 16384, bf0, 0); readB(buf1 + 16384, bf1, 1);
  mmq(0, 0, bf0);
  mmq(0, 1, bf1);
  readA(buf1, 1);
  mmq(1, 1, bf1);
  mmq(1, 0, bf0);

  asm volatile("s_waitcnt vmcnt(0) lgkmcnt(0)" ::: "memory");
  __syncthreads();

  float bb[4];
  #pragma unroll
  for(int n = 0; n < 4; ++n)
    bb[n] = bias[wh * 768 + colB0 + wc * 64 + n * 16 + fr];

  if constexpr(!OUTF32){
    short* Out = (short*)OutBase + (long)g * SLOT;
    short* Cs = lds;  // [128][256] overlay on dead staging
    #pragma unroll
    for(int ch = 0; ch < 2; ++ch){
      __syncthreads();
      if(wr == ch){
        #pragma unroll
        for(int m = 0; m < 8; ++m)
          #pragma unroll
          for(int n = 0; n < 4; ++n)
            #pragma unroll
            for(int r2 = 0; r2 < 4; ++r2){
              int row = m * 16 + (lane >> 4) * 4 + r2;
              int c = wc * 64 + n * 16 + fr;
              Cs[row * 256 + (c ^ (((row >> 2) & 3) << 4))] = f2bf(acc[m][n][r2] + bb[n]);
            }
      }
      __syncthreads();
      #pragma unroll
      for(int i = 0; i < 8; ++i){
        int idx = i * 512 + tid;
        int row = idx >> 5, cl = (idx & 31) * 8;
        s16x8 v = *(const s16x8*)&Cs[row * 256 + (cl ^ (((row >> 2) & 3) << 4))];
        *(s16x8*)&Out[(rowA0 + ch * 128 + row) * 768 + colB0 + cl] = v;
      }
    }
  } else {
    float* Co = (float*)OutBase;
    #pragma unroll
    for(int m = 0; m < 8; ++m)
      #pragma unroll
      for(int n = 0; n < 4; ++n)
        #pragma unroll
        for(int r2 = 0; r2 < 4; ++r2){
          const long row = rowA0 + wr * 128 + m * 16 + (lane >> 4) * 4 + r2;
          const int col = colB0 + wc * 64 + n * 16 + fr;
          Co[row * 768 + col] = acc[m][n][r2] + bb[n];
        }
  }
}

// ============ FALLBACK: proven round-4 ring-2 BK=32 kernel ============
__global__ __launch_bounds__(512, 1) void gemm256(const short* __restrict__ A,
                                                  const short* __restrict__ W,
                                                  const float* __restrict__ bias,
                                                  short* __restrict__ OutBase,
                                                  int hBase, int nSub, int pSub){
  __shared__ short lds[2][16384];
  const int tid = threadIdx.x, lane = tid & 63, w = tid >> 6;
  const int wr = w >> 2, wc = w & 3;
  const int bid = xcd_swz(blockIdx.x, nSub * 768);
  const int g = bid / 768, rb = bid - g * 768;
  const int rowBlk = rb / 3, colBlk = rb - rowBlk * 3;
  const long rowA0 = (long)rowBlk * 256;
  const int colB0 = colBlk * 256;
  const int wh = (g == pSub) ? 12 : hBase + g;
  const short* Bm = W + (long)wh * 589824L;
  short* Out = OutBase + (long)g * SLOT;

  const int sr0 = w * 32 + (lane >> 2);
  const int sr1 = sr0 + 16;
  const int scol = (lane & 3) * 8;
  const int sc0 = swz32(sr0, scol);
  const int sc1 = swz32(sr1, scol);
  const short* Ar0 = A + (rowA0 + sr0) * 768;
  const short* Ar1 = A + (rowA0 + sr1) * 768;
  const short* Br0 = Bm + (long)(colB0 + sr0) * 768;
  const short* Br1 = Bm + (long)(colB0 + sr1) * 768;

  f32x4 acc[8][4] = {};
  s16x8 af[4], bf0[2], bf1[2];
  const int fr = lane & 15, fc = (lane >> 4) * 8;

  auto stage = [&](int b, int kt){
    short* Al = &lds[b][0];
    short* Bl = &lds[b][8192];
    gld_lds16(Ar0 + kt + sc0, Al + (w * 2) * 512);
    gld_lds16(Ar1 + kt + sc1, Al + (w * 2 + 1) * 512);
    gld_lds16(Br0 + kt + sc0, Bl + (w * 2) * 512);
    gld_lds16(Br1 + kt + sc1, Bl + (w * 2 + 1) * 512);
  };

  stage(0, 0);
  for(int t = 0; t < 24; ++t){
    if(t < 23){
      stage((t + 1) & 1, (t + 1) * 32);
      asm volatile("s_waitcnt vmcnt(4)\n\ts_barrier" ::: "memory");
    } else {
      asm volatile("s_waitcnt vmcnt(0)\n\ts_barrier" ::: "memory");
    }
    const short* Al = &lds[t & 1][0];
    const short* Bl = &lds[t & 1][8192];

    auto loadA = [&](int mh){
      #pragma unroll
      for(int m = 0; m < 4; ++m){
        int row = wr * 128 + (mh * 4 + m) * 16 + fr;
        af[m] = *(const s16x8*)&Al[row * 32 + swz32(row, fc)];
      }
    };
    auto loadB = [&](int nh, s16x8* bf){
      #pragma unroll
      for(int n = 0; n < 2; ++n){
        int row = wc * 64 + (nh * 2 + n) * 16 + fr;
        bf[n] = *(const s16x8*)&Bl[row * 32 + swz32(row, fc)];
      }
    };
    auto mm = [&](int mh, int nh, s16x8* bf){
      __builtin_amdgcn_s_setprio(1);
      #pragma unroll
      for(int m = 0; m < 4; ++m)
        #pragma unroll
        for(int n = 0; n < 2; ++n)
          acc[mh * 4 + m][nh * 2 + n] = __builtin_amdgcn_mfma_f32_16x16x32_bf16(
              af[m], bf[n], acc[mh * 4 + m][nh * 2 + n], 0, 0, 0);
      __builtin_amdgcn_s_setprio(0);
    };

    loadA(0); loadB(0, bf0); mm(0, 0, bf0);
    loadB(1, bf1);           mm(0, 1, bf1);
    loadA(1);                mm(1, 1, bf1);
    loadB(0, bf0);           mm(1, 0, bf0);
    asm volatile("s_barrier" ::: "memory");
  }

  float bb[4];
  #pragma unroll
  for(int n = 0; n < 4; ++n)
    bb[n] = bias[wh * 768 + colB0 + wc * 64 + n * 16 + fr];

  short* Cs = &lds[0][0];
  #pragma unroll
  for(int ch = 0; ch < 2; ++ch){
    __syncthreads();
    if(wr == ch){
      #pragma unroll
      for(int m = 0; m < 8; ++m)
        #pragma unroll
        for(int n = 0; n < 4; ++n)
          #pragma unroll
          for(int r2 = 0; r2 < 4; ++r2){
            int row = m * 16 + (lane >> 4) * 4 + r2;
            int c = wc * 64 + n * 16 + fr;
            Cs[row * 256 + (c ^ (((row >> 2) & 3) << 4))] = f2bf(acc[m][n][r2] + bb[n]);
          }
    }
    __syncthreads();
    #pragma unroll
    for(int i = 0; i < 8; ++i){
      int idx = i * 512 + tid;
      int row = idx >> 5, cl = (idx & 31) * 8;
      s16x8 v = *(const s16x8*)&Cs[row * 256 + (cl ^ (((row >> 2) & 3) << 4))];
      *(s16x8*)&Out[(rowA0 + ch * 128 + row) * 768 + colB0 + cl] = v;
    }
  }
}

// ------ fallback final (fp32 out, 128² 2-phase, proven) ------
__global__ __launch_bounds__(256, 2) void gemm_f32(const short* __restrict__ A,
                                                   const short* __restrict__ B,
                                                   const float* __restrict__ bias,
                                                   float* __restrict__ Cout){
  __shared__ short smem[4 * 8192];
  const int tid = threadIdx.x, lane = tid & 63, w = tid >> 6;
  const int wr = w >> 1, wc = w & 1;
  const int nCol = 6;
  const int xcd = blockIdx.x & 7, loc = blockIdx.x >> 3;
  const int width = nCol << 3;
  const int gid = loc / width, rem = loc % width;
  const int rowBlk = (xcd << 6) + (gid << 3) + (rem & 7);
  const int colBlk = rem >> 3;
  const long rowA0 = (long)rowBlk << 7;
  const long colB0 = (long)colBlk << 7;
  const int lr = lane >> 3;
  const int sA = swz64(lr, (lane & 7) * 8);

  f32x4 acc[4][4] = {};
  auto stage = [&](int b, int kt){
    short* As = smem + b * 16384;
    #pragma unroll
    for(int it = 0; it < 4; ++it){
      int r = it * 32 + w * 8;
      gld_lds16(&A[(rowA0 + r + lr) * 768 + kt + sA], &As[r * 64]);
      gld_lds16(&B[(colB0 + r + lr) * 768 + kt + sA], &As[8192 + r * 64]);
    }
  };

  stage(0, 0);
  for(int t = 0; t < 12; ++t){
    const int cur = t & 1;
    if(t < 11){
      stage(cur ^ 1, (t + 1) * 64);
      asm volatile("s_waitcnt vmcnt(8)\n\ts_barrier" ::: "memory");
    } else {
      asm volatile("s_waitcnt vmcnt(0)\n\ts_barrier" ::: "memory");
    }
    const short* As = smem + cur * 16384;
    const short* Bs = As + 8192;
    #pragma unroll
    for(int kk = 0; kk < 2; ++kk){
      s16x8 af[4], bfr[4];
      #pragma unroll
      for(int m = 0; m < 4; ++m){
        int row = wr * 64 + m * 16 + (lane & 15);
        af[m] = *(const s16x8*)&As[row * 64 + swz64(row, kk * 32 + (lane >> 4) * 8)];
      }
      #pragma unroll
      for(int n = 0; n < 4; ++n){
        int row = wc * 64 + n * 16 + (lane & 15);
        bfr[n] = *(const s16x8*)&Bs[row * 64 + swz64(row, kk * 32 + (lane >> 4) * 8)];
      }
      #pragma unroll
      for(int m = 0; m < 4; ++m)
        #pragma unroll
        for(int n = 0; n < 4; ++n)
          acc[m][n] = __builtin_amdgcn_mfma_f32_16x16x32_bf16(af[m], bfr[n], acc[m][n], 0, 0, 0);
    }
    asm volatile("s_barrier" ::: "memory");
  }

  const long crow0 = rowA0 + wr * 64;
  const long ccol0 = colB0 + wc * 64;
  #pragma unroll
  for(int n = 0; n < 4; ++n){
    const long col = ccol0 + n * 16 + (lane & 15);
    const float bbv = bias[col];
    #pragma unroll
    for(int m = 0; m < 4; ++m)
      #pragma unroll
      for(int r = 0; r < 4; ++r){
        const long row = crow0 + m * 16 + (lane >> 4) * 4 + r;
        Cout[row * 768 + col] = acc[m][n][r] + bbv;
      }
  }
}

// ------ fused per-(h,s): scores = Q@Xs^T (4-phase) ; V' = scores@P ; -> Cat ------
__global__ __launch_bounds__(256, 2) void attn_k(const short* __restrict__ Q,
                                                 const short* __restrict__ P,
                                                 const short* __restrict__ X,
                                                 short* __restrict__ Cat,
                                                 int h0, int nH){
  __shared__ short smem[4 * 8192];   // 2 bufs × (Q 8192 | X 8192 shorts)
  const int tid = threadIdx.x, lane = tid & 63, w = tid >> 6;
  const int wr = w >> 1, wc = w & 1;
  const int nwg = nH << 9;
  const int bid = xcd_swz(blockIdx.x, nwg);
  const int s = bid / nH, hi = bid - s * nH, h = h0 + hi;
  const long row0 = (long)s * 128;

  // P-tile prefetch to regs (consumed after QK^T)
  const int pm = tid >> 3, pt0 = (tid & 7) * 8;
  s16x8 pv[4];
  #pragma unroll
  for(int i = 0; i < 4; ++i)
    pv[i] = *(const s16x8*)&P[(row0 + pm + i * 32) * 768L + h * 64 + pt0];

  const short* Qh = Q + (long)hi * SLOT;
  const int srow = tid >> 3;                    // 0..31
  const int ssw = swz64(srow, (tid & 7) * 8);
  const short* gQ = Qh + (row0 + srow) * 768 + ssw;
  const short* gX = X + (row0 + srow) * 768 + ssw;

  // stage quarter j (rows j*32..j*32+31 of both Q and X): 2 gld_lds/thread
  auto stageQX = [&](int b, int kt, int j){
    short* As = smem + b * 16384;
    gld_lds16(gQ + (long)j * 24576 + kt, As + j * 2048 + w * 512);
    gld_lds16(gX + (long)j * 24576 + kt, As + 8192 + j * 2048 + w * 512);
  };

  f32x4 acc[4][4] = {};
  const int fr = lane & 15, fcb = (lane >> 4) * 8;
  s16x8 af[2][2], bf[2][2];

  auto readAq = [&](int b, int mh){
    const short* Al = smem + b * 16384;
    #pragma unroll
    for(int m = 0; m < 2; ++m){
      int row = wr * 64 + (mh * 2 + m) * 16 + fr;
      #pragma unroll
      for(int kk = 0; kk < 2; ++kk)
        af[m][kk] = *(const s16x8*)&Al[row * 64 + swz64(row, kk * 32 + fcb)];
    }
  };
  auto readBq = [&](int b, int nh){
    const short* Bl = smem + b * 16384 + 8192;
    #pragma unroll
    for(int n = 0; n < 2; ++n){
      int row = wc * 64 + (nh * 2 + n) * 16 + fr;
      #pragma unroll
      for(int kk = 0; kk < 2; ++kk)
        bf[n][kk] = *(const s16x8*)&Bl[row * 64 + swz64(row, kk * 32 + fcb)];
    }
  };
  auto mmq = [&](int mh, int nh){
    asm volatile("s_waitcnt lgkmcnt(0)" ::: "memory");
    __builtin_amdgcn_s_setprio(1);
    #pragma unroll
    for(int m = 0; m < 2; ++m)
      #pragma unroll
      for(int n = 0; n < 2; ++n)
        #pragma unroll
        for(int kk = 0; kk < 2; ++kk)
          acc[mh*2+m][nh*2+n] = __builtin_amdgcn_mfma_f32_16x16x32_bf16(
              af[m][kk], bf[n][kk], acc[mh*2+m][nh*2+n], 0, 0, 0);
    __builtin_amdgcn_s_setprio(0);
  };

  stageQX(0, 0, 0); stageQX(0, 0, 1); stageQX(0, 0, 2); stageQX(0, 0, 3);

  for(int t = 0; t < 12; ++t){
    const int b = t & 1, nb = b ^ 1;
    const int kt1 = (t + 1) * 64;
    if(t < 11){
      stageQX(nb, kt1, 0);
      asm volatile("s_waitcnt vmcnt(2)" ::: "memory");
    } else {
      asm volatile("s_waitcnt vmcnt(0)" ::: "memory");
    }
    asm volatile("s_barrier" ::: "memory");
    readAq(b, 0); readBq(b, 0);
    mmq(0, 0);
    asm volatile("s_barrier" ::: "memory");
    readBq(b, 1);
    if(t < 11) stageQX(nb, kt1, 1);
    asm volatile("s_barrier" ::: "memory");
    mmq(0, 1);
    asm volatile("s_barrier" ::: "memory");
    readAq(b, 1);
    if(t < 11) stageQX(nb, kt1, 2);
    asm volatile("s_barrier" ::: "memory");
    mmq(1, 1);
    asm volatile("s_barrier" ::: "memory");
    readBq(b, 0);
    if(t < 11) stageQX(nb, kt1, 3);
    asm volatile("s_barrier" ::: "memory");
    mmq(1, 0);
    asm volatile("s_barrier" ::: "memory");
  }

  asm volatile("s_waitcnt vmcnt(0) lgkmcnt(0)" ::: "memory");
  __syncthreads();

  short* Pt = smem;           // [64][128]
  short* Vt = smem + 8192;    // [128][64]
  short* Ss = smem + 16384;   // [128][128]

  #pragma unroll
  for(int m = 0; m < 4; ++m)
    #pragma unroll
    for(int n = 0; n < 4; ++n)
      #pragma unroll
      for(int r = 0; r < 4; ++r){
        int row = wr * 64 + m * 16 + (lane >> 4) * 4 + r;
        int c = wc * 64 + n * 16 + (lane & 15);
        Ss[row * 128 + swz64(row, c)] = f2bf(acc[m][n][r]);
      }
  #pragma unroll
  for(int i = 0; i < 4; ++i)
    #pragma unroll
    for(int j = 0; j < 8; ++j){
      int trow = pt0 + j;
      int mc = pm + i * 32;
      Pt[trow * 128 + swz64(trow, mc)] = pv[i][j];
    }
  __syncthreads();

  f32x4 accv[2][4] = {};
  #pragma unroll
  for(int kk = 0; kk < 4; ++kk){
    s16x8 a2[2], b4[4];
    #pragma unroll
    for(int m = 0; m < 2; ++m){
      int row = w * 32 + m * 16 + (lane & 15);
      a2[m] = *(const s16x8*)&Ss[row * 128 + swz64(row, kk * 32 + (lane >> 4) * 8)];
    }
    #pragma unroll
    for(int n = 0; n < 4; ++n){
      int trow = n * 16 + (lane & 15);
      b4[n] = *(const s16x8*)&Pt[trow * 128 + swz64(trow, kk * 32 + (lane >> 4) * 8)];
    }
    #pragma unroll
    for(int m = 0; m < 2; ++m)
      #pragma unroll
      for(int n = 0; n < 4; ++n)
        accv[m][n] = __builtin_amdgcn_mfma_f32_16x16x32_bf16(a2[m], b4[n], accv[m][n], 0, 0, 0);
  }

  #pragma unroll
  for(int m = 0; m < 2; ++m)
    #pragma unroll
    for(int n = 0; n < 4; ++n)
      #pragma unroll
      for(int r = 0; r < 4; ++r){
        int row = w * 32 + m * 16 + (lane >> 4) * 4 + r;
        int c = n * 16 + (lane & 15);
        Vt[row * 64 + swz64(row, c)] = f2bf(accv[m][n][r]);
      }
  __syncthreads();
  #pragma unroll
  for(int k2 = 0; k2 < 4; ++k2){
    int row = k2 * 32 + (tid >> 3);
    int cl = (tid & 7) * 8;
    s16x8 v = *(const s16x8*)&Vt[row * 64 + swz64(row, cl)];
    *(s16x8*)&Cat[(row0 + row) * 768L + h * 64 + cl] = v;
  }
}

extern "C" void kernel_launch(void* const* d_in, const int* in_sizes, int n_in,
                              void* d_out, int out_size, void* d_ws, size_t ws_size,
                              hipStream_t stream){
  const float* x  = (const float*)d_in[0];
  const float* Wq = (const float*)d_in[1];
  const float* bq = (const float*)d_in[2];
  const float* Wv = (const float*)d_in[3];
  const float* bv = (const float*)d_in[4];
  const float* Wf = (const float*)d_in[5];
  const float* bfv= (const float*)d_in[6];

  const float rsqE = 0.03608439182435161f;  // 1/sqrt(768)
  char* ws = (char*)d_ws;

  short* Xb  = (short*)(ws);
  short* Cat = (short*)(ws + 100663296L);
  short* Wb  = (short*)(ws + 201326592L);   // [13*768][768] bf16
  short* Wfb = (short*)(ws + 216662016L);
  float* bQP = (float*)(ws + 217841664L);   // [9984]
  float* cv  = (float*)(ws + 217881600L);
  short* QS  = (short*)(ws + 217884672L);   // (G+1) slots of [65536][768]

  const size_t QOFF = 217884672ULL;
  int G = 1;
  const int cands[5] = {12, 6, 4, 3, 2};
  for(int i = 0; i < 5; ++i)
    if(ws_size >= QOFF + (size_t)(cands[i] + 1) * 100663296ULL){ G = cands[i]; break; }
  short* Pall = QS + (long)G * SLOT;

  // opt-in to 128 KiB dynamic LDS; fall back if unavailable
  bool deep =
      hipFuncSetAttribute(reinterpret_cast<const void*>(&gemm8p<false>),
                          hipFuncAttributeMaxDynamicSharedMemorySize, 131072) == hipSuccess &&
      hipFuncSetAttribute(reinterpret_cast<const void*>(&gemm8p<true>),
                          hipFuncAttributeMaxDynamicSharedMemorySize, 131072) == hipSuccess;

  dim3 b256(256), b512(512);
  cast_bf16_k<<<24576, b256, 0, stream>>>(x,  Xb, 50331648L, 1.f);
  cast_bf16_k<<<3456,  b256, 0, stream>>>(Wq, Wb, 7077888L, 1.f);
  cast_bf16_k<<<288,   b256, 0, stream>>>(Wv, Wb + 7077888L, 589824L, rsqE);
  cast_bf16_k<<<288,   b256, 0, stream>>>(Wf, Wfb, 589824L, 1.f);
  bias_build<<<39, b256, 0, stream>>>(bq, bQP);
  cvec_k<<<3, b256, 0, stream>>>(Wf, bv, bfv, cv);

  const int nB = 12 / G;
  for(int b = 0; b < nB; ++b){
    const int nSub = G + (b == 0 ? 1 : 0);
    const int pSub = (b == 0) ? G : -1;
    if(deep)
      gemm8p<false><<<dim3(nSub * 768), b512, 131072, stream>>>(Xb, Wb, bQP, QS, b * G, nSub, pSub);
    else
      gemm256<<<dim3(nSub * 768), b512, 0, stream>>>(Xb, Wb, bQP, QS, b * G, nSub, pSub);
    attn_k<<<dim3(G * 512), b256, 0, stream>>>(QS, Pall, Xb, Cat, b * G, G);
  }
  if(deep)
    gemm8p<true><<<dim3(768), b512, 131072, stream>>>(Cat, Wfb, cv, d_out, 0, 1, -1);
  else
    gemm_f32<<<dim3(3072), b256, 0, stream>>>(Cat, Wfb, cv, (float*)d_out);
}